// Round 7
// baseline (132.788 us; speedup 1.0000x reference)
//
#include <hip/hip_runtime.h>
#include <hip/hip_bf16.h>
#include <stdint.h>

#define B_ 2
#define S_ 2048
#define H_ 32
#define D_ 128
#define R_ (B_*H_*S_)   // 131072 rows per tensor (head-major)
#define QKBLKS (2 * R_ / 8)
#define VSBLKS (R_ / 8)
#define NDBLKS (2 * R_ / 1024)  // zero num+den, float4 per thread
#define CPB 51                  // k-chunks (<=6 64-row tiles) per bh

typedef __bf16 bf16x8 __attribute__((ext_vector_type(8)));
typedef float  f32x16 __attribute__((ext_vector_type(16)));

#if __has_builtin(__builtin_amdgcn_exp2f)
#define EXP2F(x) __builtin_amdgcn_exp2f(x)
#else
#define EXP2F(x) exp2f(x)
#endif

#define AS1 __attribute__((address_space(1)))
#define AS3 __attribute__((address_space(3)))

__device__ __forceinline__ unsigned short f2bf(float f) {
  unsigned u = __float_as_uint(f);
  u += 0x7FFFu + ((u >> 16) & 1u);
  return (unsigned short)(u >> 16);
}

// Fused prep: [0,QKBLKS): q,k [B,S,H,D] fp32 -> [B,H,S,D] bf16 (Q gets
// scale*log2e folded); [+VSBLKS): vsum[b,h,s]=sum_d v (float4 loads);
// rest: zero num/den (float4).
__global__ __launch_bounds__(256) void prep(
    const float* __restrict__ q, const float* __restrict__ k,
    const float* __restrict__ v,
    unsigned short* __restrict__ qb, unsigned short* __restrict__ kb,
    float* __restrict__ vsum, float* __restrict__ nd, float* __restrict__ out0) {
  const int bid = blockIdx.x;
  const int t = threadIdx.x;
  if (bid == 0 && t == 0) out0[0] = 0.f;
  if (bid < QKBLKS) {
    const int rowblk = bid * 8 + (t >> 5);
    const float* src; unsigned short* dst; int r; float sc;
    if (rowblk < R_) { src = q; dst = qb; r = rowblk; sc = 0.0883883476483184f * 1.4426950408889634f; }
    else             { src = k; dst = kb; r = rowblk - R_; sc = 1.0f; }
    const int b  = r / (H_ * S_);
    const int hs = r % (H_ * S_);
    const int h  = hs / S_;
    const int s  = hs % S_;
    const size_t inoff = (((size_t)b * S_ + s) * H_ + h) * D_;
    const int lane32 = t & 31;
    const float4 v4 = *reinterpret_cast<const float4*>(src + inoff + lane32 * 4);
    ushort4 o;
    o.x = f2bf(v4.x * sc); o.y = f2bf(v4.y * sc); o.z = f2bf(v4.z * sc); o.w = f2bf(v4.w * sc);
    *reinterpret_cast<ushort4*>(dst + (size_t)r * D_ + lane32 * 4) = o;
  } else if (bid < QKBLKS + VSBLKS) {
    const int r = (bid - QKBLKS) * 8 + (t >> 5);   // 8 rows/block, 32 lanes/row
    const int lane = t & 31;
    const int b  = r / (H_ * S_);
    const int hs = r % (H_ * S_);
    const int h  = hs / S_;
    const int s  = hs % S_;
    const size_t inoff = (((size_t)b * S_ + s) * H_ + h) * D_;
    const float4 x = *reinterpret_cast<const float4*>(v + inoff + lane * 4);
    float sum = x.x + x.y + x.z + x.w;
    #pragma unroll
    for (int m = 1; m < 32; m <<= 1) sum += __shfl_xor(sum, m);
    if (lane == 0) vsum[r] = sum;
  } else {
    float4* p = reinterpret_cast<float4*>(nd);
    p[(size_t)(bid - QKBLKS - VSBLKS) * 256 + t] = float4{0.f, 0.f, 0.f, 0.f};
  }
}

// Main: block = (bh, qt 128 q-rows, uniform k-chunk of <=6 64-row k-tiles).
// RAW s_barrier (no implicit vmcnt(0) drain -- __syncthreads would kill the
// pipeline) + counted vmcnt: 3-buffer depth-2, batch kt's 5 DMAs get ~2
// iterations of cover and prefetches stay in flight ACROSS barriers (T3/T4).
// Fragment-major global_load_lds staging (bank-optimal ds_read_b128, one
// address + immediate offsets). Partial (num,den) merged via global atomics.
__global__ __launch_bounds__(256, 3) void attn_sum(
    const unsigned short* __restrict__ qg_, const unsigned short* __restrict__ kg_,
    const float* __restrict__ vsum, float* __restrict__ numb,
    float* __restrict__ denb) {
  __shared__ uint4 kbuf[3][1024];      // 3 x 16KB
  __shared__ float vsbuf[3][64];       // 3 x 256B

  // id -> (bh, chunk c): same-bh blocks share id%8 -> likely same XCD.
  const int id = blockIdx.x;
  const int y  = id >> 3;
  const int bh = (id & 7) + 8 * (y / CPB);
  const int c  = y % CPB;

  // chunk table: qt has ceil((2qt+2)/6) chunks; sizes 2..6 k-tiles.
  int qt = 15, c0 = 0;
  #pragma unroll
  for (int j = 0; j < 16; ++j) {
    const int n = (2 * j + 7) / 6;
    if (c < c0 + n) { qt = j; break; }
    c0 += n;
  }
  const int h    = c - c0;
  const int nkt  = 2 * qt + 2;
  const int nch  = (nkt + 5) / 6;
  const int bas_ = nkt / nch, rem = nkt % nch;
  const int kt0  = h * bas_ + (h < rem ? h : rem);
  const int kt1  = kt0 + bas_ + (h < rem ? 1 : 0);

  const int t  = threadIdx.x;
  const int w  = t >> 6;
  const int l  = t & 63;
  const int ln = l & 31, l5 = l >> 5;

  const size_t base = (size_t)bh * S_ * D_;
  const int qrow0 = qt * 128 + w * 32;
  const unsigned short* ksrc0 = kg_ + base;
  const float* vsrc0 = vsum + (size_t)bh * S_;

  // Q A-frags: 32 q-rows (m = lane&31), k-chunk d = kb8*16 + l5*8 .. +8.
  bf16x8 qfrag[8];
  {
    const unsigned short* qp = qg_ + base + (size_t)(qrow0 + ln) * D_ + l5 * 8;
    #pragma unroll
    for (int kb8 = 0; kb8 < 8; ++kb8)
      qfrag[kb8] = *reinterpret_cast<const bf16x8*>(qp + kb8 * 16);
  }

  // Stage one 64-row K-tile (+vsum strip): exactly 5 DMA ops per wave.
  auto stage = [&](int j, int slot) {
    const unsigned short* ksrc = ksrc0 + (size_t)j * 64 * D_;
    #pragma unroll
    for (int i = 0; i < 4; ++i) {
      const int f   = w * 256 + i * 64 + l;      // flat fragment-major chunk id
      const int ln_ = f & 31, l5_ = (f >> 5) & 1;
      const int kb8_ = (f >> 6) & 7, nb_ = (f >> 9) & 1;
      const unsigned short* src = ksrc + (nb_ * 32 + ln_) * D_ + (kb8_ * 2 + l5_) * 8;
      __builtin_amdgcn_global_load_lds(
          (const AS1 void*)src, (AS3 void*)(&kbuf[slot][f & ~63]), 16, 0, 0);
    }
    __builtin_amdgcn_global_load_lds(
        (const AS1 void*)(vsrc0 + j * 64 + l), (AS3 void*)(&vsbuf[slot][0]), 4, 0, 0);
  };

  float num[16], den[16];
  #pragma unroll
  for (int r = 0; r < 16; ++r) { num[r] = 0.f; den[r] = 0.f; }

  // Prologue: depth-2 prefetch.
  stage(kt0, 0);
  if (kt0 + 1 < kt1) stage(kt0 + 1, 1);

  int cur = 0;
  for (int kt = kt0; kt < kt1; ++kt) {
    // Drain batch kt only; leave batch kt+1 (5 ops) in flight across the
    // barrier. vmcnt completion is issue-ordered, so <=5 outstanding means
    // batch kt has fully landed in LDS.
    if (kt + 1 < kt1) asm volatile("s_waitcnt vmcnt(5)" ::: "memory");
    else              asm volatile("s_waitcnt vmcnt(0)" ::: "memory");
    __builtin_amdgcn_s_barrier();   // raw: no implicit vmcnt(0) drain
    // Prefetch kt+2 into slot (kt-1)%3 -- last read a full barrier ago.
    if (kt + 2 < kt1) stage(kt + 2, cur >= 1 ? cur - 1 : cur + 2);

    const int ktb = kt * 64;
    if (ktb <= qrow0 + 31) {               // wave-uniform causal skip
      const uint4* tbase = &kbuf[cur][l5 * 32 + ln];   // one addr, imm offsets
      #pragma unroll
      for (int nb = 0; nb < 2; ++nb) {
        const int kbase = ktb + nb * 32;
        if (kbase > qrow0 + 31) continue;
        f32x16 sacc = {0.f,0.f,0.f,0.f,0.f,0.f,0.f,0.f,
                       0.f,0.f,0.f,0.f,0.f,0.f,0.f,0.f};
        __builtin_amdgcn_s_setprio(1);
        #pragma unroll
        for (int kb8 = 0; kb8 < 8; ++kb8) {
          const bf16x8 bf = *reinterpret_cast<const bf16x8*>(&tbase[(nb * 8 + kb8) * 64]);
          sacc = __builtin_amdgcn_mfma_f32_32x32x16_bf16(qfrag[kb8], bf, sacc, 0, 0, 0);
        }
        __builtin_amdgcn_s_setprio(0);
        const float vsv = vsbuf[cur][nb * 32 + ln];
        if (kbase + 31 <= qrow0) {
          #pragma unroll
          for (int r = 0; r < 16; ++r) {
            const float e = EXP2F(sacc[r]);
            den[r] += e;
            num[r] = fmaf(e, vsv, num[r]);
          }
        } else {
          const int kgc = kbase + ln;
          #pragma unroll
          for (int r = 0; r < 16; ++r) {
            const int qgr = qrow0 + (r & 3) + 8 * (r >> 2) + 4 * l5;
            const float e = (kgc <= qgr) ? EXP2F(sacc[r]) : 0.f;
            den[r] += e;
            num[r] = fmaf(e, vsv, num[r]);
          }
        }
      }
    }
    cur = (cur == 2) ? 0 : cur + 1;
  }

  // Reduce over the 32 k-cols (lanes within each l5 half), then one atomic
  // pair per q-row from lane ln==0 of each half.
  #pragma unroll
  for (int m = 1; m < 32; m <<= 1) {
    #pragma unroll
    for (int r = 0; r < 16; ++r) {
      num[r] += __shfl_xor(num[r], m);
      den[r] += __shfl_xor(den[r], m);
    }
  }
  if (ln == 0) {
    float* nrow = numb + (size_t)bh * S_;
    float* drow = denb + (size_t)bh * S_;
    #pragma unroll
    for (int r = 0; r < 16; ++r) {
      const int qgr = qrow0 + (r & 3) + 8 * (r >> 2) + 4 * l5;
      atomicAdd(&nrow[qgr], num[r]);
      atomicAdd(&drow[qgr], den[r]);
    }
  }
}

// Finalize: sum(num/den) over all q-rows.
__global__ __launch_bounds__(256) void finalize(
    const float* __restrict__ numb, const float* __restrict__ denb,
    float* __restrict__ out) {
  const int i = blockIdx.x * 256 + threadIdx.x;
  float c = numb[i] / denb[i];
  #pragma unroll
  for (int m = 1; m < 64; m <<= 1) c += __shfl_xor(c, m);
  __shared__ float ps[4];
  if ((threadIdx.x & 63) == 0) ps[threadIdx.x >> 6] = c;
  __syncthreads();
  if (threadIdx.x == 0) atomicAdd(out, ps[0] + ps[1] + ps[2] + ps[3]);
}

extern "C" void kernel_launch(void* const* d_in, const int* in_sizes, int n_in,
                              void* d_out, int out_size, void* d_ws, size_t ws_size,
                              hipStream_t stream) {
  const float* q = (const float*)d_in[0];
  const float* k = (const float*)d_in[1];
  const float* v = (const float*)d_in[2];
  float* out = (float*)d_out;

  unsigned short* qb = (unsigned short*)d_ws;                 // 32 MiB
  unsigned short* kb = qb + (size_t)R_ * D_;                  // 32 MiB
  float* vsum = (float*)(kb + (size_t)R_ * D_);               // 512 KiB
  float* numb = vsum + R_;                                    // 512 KiB
  float* denb = numb + R_;                                    // 512 KiB

  hipLaunchKernelGGL(prep, dim3(QKBLKS + VSBLKS + NDBLKS), dim3(256), 0, stream,
                     q, k, v, qb, kb, vsum, numb, out);
  hipLaunchKernelGGL(attn_sum, dim3(64 * CPB), dim3(256), 0, stream,
                     qb, kb, vsum, numb, denb);
  hipLaunchKernelGGL(finalize, dim3(R_ / 256), dim3(256), 0, stream,
                     numb, denb, out);
}

// Round 8
// 114.351 us; speedup vs baseline: 1.1612x; 1.1612x over previous
//
#include <hip/hip_runtime.h>
#include <hip/hip_bf16.h>
#include <stdint.h>

#define B_ 2
#define S_ 2048
#define H_ 32
#define D_ 128
#define R_ (B_*H_*S_)           // 131072 rows per tensor (head-major)
#define QKB (B_ * S_ * (H_/8))  // 16384 transpose blocks per tensor
#define VSB (B_ * S_)           // 4096 vsum blocks
#define NDB (2 * R_ / 1024)     // 256 zero blocks (float4)
#define CPB 40                  // uniform k-chunks (<=8 tiles) per bh

typedef __bf16 bf16x8 __attribute__((ext_vector_type(8)));
typedef float  f32x16 __attribute__((ext_vector_type(16)));

#if __has_builtin(__builtin_amdgcn_exp2f)
#define EXP2F(x) __builtin_amdgcn_exp2f(x)
#else
#define EXP2F(x) exp2f(x)
#endif

#define AS1 __attribute__((address_space(1)))
#define AS3 __attribute__((address_space(3)))

__device__ __forceinline__ unsigned short f2bf(float f) {
  unsigned u = __float_as_uint(f);
  u += 0x7FFFu + ((u >> 16) & 1u);
  return (unsigned short)(u >> 16);
}

// Fused prep, all parts READ-contiguous (reads stall, writes don't):
//  [0, 2*QKB): q,k [B,S,H,D] fp32 -> [B,H,S,D] bf16. Block reads 8 h-rows of
//    one (b,s) = 4KB contiguous; writes 8 x 256B scattered. Q gets
//    scale*log2e folded in.
//  [+VSB): vsum[b,h,s] = sum_d v[b,s,h,d]. Block reads one (b,s) panel
//    (16KB contiguous), 8 lanes per h-row, shfl-reduce, 32 scalar writes.
//  [+NDB): zero num/den (float4).
__global__ __launch_bounds__(256) void prep(
    const float* __restrict__ q, const float* __restrict__ k,
    const float* __restrict__ v,
    unsigned short* __restrict__ qb, unsigned short* __restrict__ kb,
    float* __restrict__ vsum, float* __restrict__ nd, float* __restrict__ out0) {
  const int bid = blockIdx.x;
  const int t = threadIdx.x;
  if (bid == 0 && t == 0) out0[0] = 0.f;
  if (bid < 2 * QKB) {
    const int which = bid >= QKB;
    const int i2 = which ? bid - QKB : bid;
    const float* src = which ? k : q;
    unsigned short* dst = which ? kb : qb;
    const float sc = which ? 1.0f : 0.0883883476483184f * 1.4426950408889634f;
    const int b   = i2 / (S_ * 4);
    const int rem = i2 % (S_ * 4);
    const int s   = rem >> 2;
    const int h   = (rem & 3) * 8 + (t >> 5);
    const int lane32 = t & 31;
    const float4 v4 = *reinterpret_cast<const float4*>(
        src + (((size_t)b * S_ + s) * H_ + h) * D_ + lane32 * 4);
    ushort4 o;
    o.x = f2bf(v4.x * sc); o.y = f2bf(v4.y * sc);
    o.z = f2bf(v4.z * sc); o.w = f2bf(v4.w * sc);
    *reinterpret_cast<ushort4*>(
        dst + (((size_t)b * H_ + h) * S_ + s) * D_ + lane32 * 4) = o;
  } else if (bid < 2 * QKB + VSB) {
    const int i2 = bid - 2 * QKB;
    const int b = i2 / S_, s = i2 % S_;
    const int h = t >> 3, i = t & 7;   // 8 lanes per h-row
    const float* p = v + (((size_t)b * S_ + s) * H_ + h) * D_ + i * 16;
    const float4 a0 = *reinterpret_cast<const float4*>(p + 0);
    const float4 a1 = *reinterpret_cast<const float4*>(p + 4);
    const float4 a2 = *reinterpret_cast<const float4*>(p + 8);
    const float4 a3 = *reinterpret_cast<const float4*>(p + 12);
    float sum = (a0.x+a0.y+a0.z+a0.w) + (a1.x+a1.y+a1.z+a1.w)
              + (a2.x+a2.y+a2.z+a2.w) + (a3.x+a3.y+a3.z+a3.w);
    sum += __shfl_xor(sum, 1);
    sum += __shfl_xor(sum, 2);
    sum += __shfl_xor(sum, 4);
    if (i == 0) vsum[((size_t)b * H_ + h) * S_ + s] = sum;
  } else {
    float4* p = reinterpret_cast<float4*>(nd);
    p[(size_t)(bid - 2 * QKB - VSB) * 256 + t] = float4{0.f, 0.f, 0.f, 0.f};
  }
}

// Main: block = (bh, qt 128 q-rows, uniform k-chunk of <=8 64-row k-tiles).
// LDS swizzle: physical 16B-chunk p of row r holds logical chunk c = p^(r&15)
// (involution). Staging: each global_load_lds covers 4 FULL rows = 1KB
// contiguous global (permutation stays within 256B rows) -> 8 L2 lines per
// instruction, coalesced -- this removes the 8x L2-transaction inflation that
// R4-R7's fragment-major staging paid. Reads: lane ln reads chunk
// (kb8*2+l5)^(ln&15) -> 16 distinct positions per 16 lanes = bank-balanced.
// Depth-1 double buffer + __syncthreads (best measured config, R6).
__global__ __launch_bounds__(256, 4) void attn_sum(
    const unsigned short* __restrict__ qg_, const unsigned short* __restrict__ kg_,
    const float* __restrict__ vsum, float* __restrict__ numb,
    float* __restrict__ denb) {
  __shared__ uint4 kbuf[2][1024];      // 2 x 16KB
  __shared__ float vsbuf[2][64];       // 2 x 256B

  // id -> (bh, chunk c): same-bh blocks share id%8 -> likely same XCD.
  const int id = blockIdx.x;
  const int y  = id >> 3;
  const int bh = (id & 7) + 8 * (y / CPB);
  const int c  = y % CPB;

  // chunk table: qt 0-3 -> 1 chunk; 4-7 -> 2; 8-11 -> 3; 12-15 -> 4.
  int qt, h, nch;
  if (c < 4)       { qt = c;                 h = 0;            nch = 1; }
  else if (c < 12) { qt = 4 + ((c - 4) >> 1);  h = (c - 4) & 1;  nch = 2; }
  else if (c < 24) { qt = 8 + (c - 12) / 3;    h = (c - 12) % 3; nch = 3; }
  else             { qt = 12 + ((c - 24) >> 2); h = (c - 24) & 3; nch = 4; }
  const int nkt  = 2 * qt + 2;
  const int bas_ = nkt / nch, rem = nkt % nch;
  const int kt0  = h * bas_ + (h < rem ? h : rem);
  const int kt1  = kt0 + bas_ + (h < rem ? 1 : 0);

  const int t  = threadIdx.x;
  const int w  = t >> 6;
  const int l  = t & 63;
  const int ln = l & 31, l5 = l >> 5;

  const size_t base = (size_t)bh * S_ * D_;
  const int qrow0 = qt * 128 + w * 32;
  const unsigned short* ksrc0 = kg_ + base;
  const float* vsrc0 = vsum + (size_t)bh * S_;

  // Q A-frags: 32 q-rows (m = lane&31), k-chunk d = kb8*16 + l5*8 .. +8.
  bf16x8 qfrag[8];
  {
    const unsigned short* qp = qg_ + base + (size_t)(qrow0 + ln) * D_ + l5 * 8;
    #pragma unroll
    for (int kb8 = 0; kb8 < 8; ++kb8)
      qfrag[kb8] = *reinterpret_cast<const bf16x8*>(qp + kb8 * 16);
  }

  // Stage one 64-row K-tile (+vsum strip): 5 DMAs/wave, COALESCED source.
  auto stage = [&](int j, int slot) {
    const unsigned short* ksrc = ksrc0 + (size_t)j * 64 * D_;
    #pragma unroll
    for (int i = 0; i < 4; ++i) {
      const int idx = w * 256 + i * 64 + l;   // physical 16B slot
      const int r   = idx >> 4;
      const int p   = idx & 15;
      const int cc  = p ^ (r & 15);           // logical chunk stored here
      const unsigned short* src = ksrc + r * D_ + cc * 8;
      __builtin_amdgcn_global_load_lds(
          (const AS1 void*)src, (AS3 void*)(&kbuf[slot][idx & ~63]), 16, 0, 0);
    }
    __builtin_amdgcn_global_load_lds(
        (const AS1 void*)(vsrc0 + j * 64 + l), (AS3 void*)(&vsbuf[slot][0]), 4, 0, 0);
  };

  float num[16], den[16];
  #pragma unroll
  for (int r = 0; r < 16; ++r) { num[r] = 0.f; den[r] = 0.f; }

  stage(kt0, 0);
  int cur = 0;
  const int xr = ln & 15;
  for (int kt = kt0; kt < kt1; ++kt) {
    asm volatile("s_waitcnt vmcnt(0)" ::: "memory");
    __syncthreads();
    if (kt + 1 < kt1) stage(kt + 1, cur ^ 1);

    const int ktb = kt * 64;
    if (ktb <= qrow0 + 31) {               // wave-uniform causal skip
      #pragma unroll
      for (int nb = 0; nb < 2; ++nb) {
        const int kbase = ktb + nb * 32;
        if (kbase > qrow0 + 31) continue;
        const uint4* rowb = &kbuf[cur][(nb * 32 + ln) * 16];
        f32x16 sacc = {0.f,0.f,0.f,0.f,0.f,0.f,0.f,0.f,
                       0.f,0.f,0.f,0.f,0.f,0.f,0.f,0.f};
        __builtin_amdgcn_s_setprio(1);
        #pragma unroll
        for (int kb8 = 0; kb8 < 8; ++kb8) {
          const bf16x8 bf = *reinterpret_cast<const bf16x8*>(&rowb[(kb8 * 2 + l5) ^ xr]);
          sacc = __builtin_amdgcn_mfma_f32_32x32x16_bf16(qfrag[kb8], bf, sacc, 0, 0, 0);
        }
        __builtin_amdgcn_s_setprio(0);
        const float vsv = vsbuf[cur][nb * 32 + ln];
        if (kbase + 31 <= qrow0) {
          #pragma unroll
          for (int r = 0; r < 16; ++r) {
            const float e = EXP2F(sacc[r]);
            den[r] += e;
            num[r] = fmaf(e, vsv, num[r]);
          }
        } else {
          const int kgc = kbase + ln;
          #pragma unroll
          for (int r = 0; r < 16; ++r) {
            const int qgr = qrow0 + (r & 3) + 8 * (r >> 2) + 4 * l5;
            const float e = (kgc <= qgr) ? EXP2F(sacc[r]) : 0.f;
            den[r] += e;
            num[r] = fmaf(e, vsv, num[r]);
          }
        }
      }
    }
    cur ^= 1;
  }

  // Reduce over the 32 k-cols (lanes within each l5 half), then one atomic
  // pair per q-row from lane ln==0 of each half.
  #pragma unroll
  for (int m = 1; m < 32; m <<= 1) {
    #pragma unroll
    for (int r = 0; r < 16; ++r) {
      num[r] += __shfl_xor(num[r], m);
      den[r] += __shfl_xor(den[r], m);
    }
  }
  if (ln == 0) {
    float* nrow = numb + (size_t)bh * S_;
    float* drow = denb + (size_t)bh * S_;
    #pragma unroll
    for (int r = 0; r < 16; ++r) {
      const int qgr = qrow0 + (r & 3) + 8 * (r >> 2) + 4 * l5;
      atomicAdd(&nrow[qgr], num[r]);
      atomicAdd(&drow[qgr], den[r]);
    }
  }
}

// Finalize: sum(num/den) over all q-rows.
__global__ __launch_bounds__(256) void finalize(
    const float* __restrict__ numb, const float* __restrict__ denb,
    float* __restrict__ out) {
  const int i = blockIdx.x * 256 + threadIdx.x;
  float c = numb[i] / denb[i];
  #pragma unroll
  for (int m = 1; m < 64; m <<= 1) c += __shfl_xor(c, m);
  __shared__ float ps[4];
  if ((threadIdx.x & 63) == 0) ps[threadIdx.x >> 6] = c;
  __syncthreads();
  if (threadIdx.x == 0) atomicAdd(out, ps[0] + ps[1] + ps[2] + ps[3]);
}

extern "C" void kernel_launch(void* const* d_in, const int* in_sizes, int n_in,
                              void* d_out, int out_size, void* d_ws, size_t ws_size,
                              hipStream_t stream) {
  const float* q = (const float*)d_in[0];
  const float* k = (const float*)d_in[1];
  const float* v = (const float*)d_in[2];
  float* out = (float*)d_out;

  unsigned short* qb = (unsigned short*)d_ws;                 // 32 MiB
  unsigned short* kb = qb + (size_t)R_ * D_;                  // 32 MiB
  float* vsum = (float*)(kb + (size_t)R_ * D_);               // 512 KiB
  float* numb = vsum + R_;                                    // 512 KiB
  float* denb = numb + R_;                                    // 512 KiB

  hipLaunchKernelGGL(prep, dim3(2 * QKB + VSB + NDB), dim3(256), 0, stream,
                     q, k, v, qb, kb, vsum, numb, out);
  hipLaunchKernelGGL(attn_sum, dim3(64 * CPB), dim3(256), 0, stream,
                     qb, kb, vsum, numb, denb);
  hipLaunchKernelGGL(finalize, dim3(R_ / 256), dim3(256), 0, stream,
                     numb, denb, out);
}